// Round 4
// baseline (370.465 us; speedup 1.0000x reference)
//
#include <hip/hip_runtime.h>
#include <math.h>

#define NN 4096
#define FF 32
#define DD 16
#define EE 65536

__device__ __forceinline__ int l_of(int i){ return (i==0)?0:(i<4)?1:(i<9)?2:3; }
__device__ __forceinline__ float silu(float v){ return v/(1.f+expf(-v)); }

// ---------- x = per_l_linear(node_feats, W_up) ----------
__global__ __launch_bounds__(512) void k_x(const float* __restrict__ feats,
        const float* __restrict__ Wup, float* __restrict__ x){
  __shared__ float sF[FF*DD];
  __shared__ float sW[4*FF*FF];
  int n = blockIdx.x, t = threadIdx.x;
  sF[t] = feats[(size_t)n*FF*DD + t];
  for (int k=t;k<4*FF*FF;k+=512) sW[k]=Wup[k];
  __syncthreads();
  int f = t>>4, i = t&15;
  const float* W = &sW[l_of(i)*FF*FF];
  float a=0.f;
  #pragma unroll
  for (int c=0;c<FF;c++) a += sF[c*DD+i]*W[c*FF+f];
  x[(size_t)n*FF*DD + t] = a;
}

// ---------- spherical harmonics (edge-parallel) ----------
__global__ __launch_bounds__(256) void k_Y(const float* __restrict__ vec, float* __restrict__ Yp){
  int e = blockIdx.x*256+threadIdx.x;
  if (e>=EE) return;
  float vx=vec[(size_t)e*3+0], vy=vec[(size_t)e*3+1], vz=vec[(size_t)e*3+2];
  float r2=vx*vx+vy*vy+vz*vz;
  float inv = (r2==0.f)?1.f:rsqrtf(r2);
  float X=vx*inv, Y=vy*inv, Z=vz*inv;
  const float s3=1.7320508075688772f, s5=2.23606797749979f, s7=2.6457513110645907f;
  const float s15=3.872983346207417f, s42=6.48074069840786f, s70=8.366600265340756f, s105=10.246950765959598f;
  float y[16];
  y[0]=s3*X; y[1]=s3*Y; y[2]=s3*Z;
  y[3]=s15*X*Y; y[4]=s15*Y*Z; y[5]=0.5f*s5*(3.f*Z*Z-1.f); y[6]=s15*X*Z; y[7]=0.5f*s15*(X*X-Y*Y);
  y[8]=0.25f*s70*Y*(3.f*X*X-Y*Y); y[9]=s105*X*Y*Z; y[10]=0.25f*s42*Y*(5.f*Z*Z-1.f);
  y[11]=0.5f*s7*Z*(5.f*Z*Z-3.f); y[12]=0.25f*s42*X*(5.f*Z*Z-1.f);
  y[13]=0.5f*s105*Z*(X*X-Y*Y); y[14]=0.25f*s70*X*(X*X-3.f*Y*Y);
  y[15]=0.f;
  #pragma unroll
  for(int q=0;q<4;q++) *(float4*)&Yp[(size_t)e*16+q*4] = *(float4*)&y[q*4];
}

// ---------- radial MLP -> mix (E, 64, 4) ----------
__global__ __launch_bounds__(256) void k_mix(const float* __restrict__ rad,
    const float* __restrict__ W1, const float* __restrict__ W2,
    const float* __restrict__ W3, const float* __restrict__ W4,
    float* __restrict__ mix){
  __shared__ float sRadT[8*68];
  __shared__ float sW1[8*64];
  __shared__ float sHA[64*68];
  __shared__ float sHB[64*68];
  int t = threadIdx.x;
  int be = blockIdx.x*64;
  for (int k=t;k<8*64;k+=256) sW1[k]=W1[k];
  for (int idx=t; idx<64*8; idx+=256){ int e=idx>>3, k=idx&7; sRadT[k*68+e]=rad[(size_t)(be+e)*8+k]; }
  __syncthreads();
  int e0 = (t>>4)*4, j0 = (t&15)*4;
  {
    float acc[4][4];
    #pragma unroll
    for(int a=0;a<4;a++){ acc[a][0]=0;acc[a][1]=0;acc[a][2]=0;acc[a][3]=0; }
    #pragma unroll
    for(int k=0;k<8;k++){
      float4 h = *(const float4*)&sRadT[k*68+e0];
      float4 w = *(const float4*)&sW1[k*64+j0];
      acc[0][0]+=h.x*w.x; acc[0][1]+=h.x*w.y; acc[0][2]+=h.x*w.z; acc[0][3]+=h.x*w.w;
      acc[1][0]+=h.y*w.x; acc[1][1]+=h.y*w.y; acc[1][2]+=h.y*w.z; acc[1][3]+=h.y*w.w;
      acc[2][0]+=h.z*w.x; acc[2][1]+=h.z*w.y; acc[2][2]+=h.z*w.z; acc[2][3]+=h.z*w.w;
      acc[3][0]+=h.w*w.x; acc[3][1]+=h.w*w.y; acc[3][2]+=h.w*w.z; acc[3][3]+=h.w*w.w;
    }
    #pragma unroll
    for(int b=0;b<4;b++){
      float4 v; v.x=silu(acc[0][b]); v.y=silu(acc[1][b]); v.z=silu(acc[2][b]); v.w=silu(acc[3][b]);
      *(float4*)&sHA[(j0+b)*68+e0] = v;
    }
  }
  __syncthreads();
  {
    float acc[4][4];
    #pragma unroll
    for(int a=0;a<4;a++){ acc[a][0]=0;acc[a][1]=0;acc[a][2]=0;acc[a][3]=0; }
    for(int k=0;k<64;k++){
      float4 h = *(const float4*)&sHA[k*68+e0];
      float4 w = *(const float4*)&W2[k*64+j0];
      acc[0][0]+=h.x*w.x; acc[0][1]+=h.x*w.y; acc[0][2]+=h.x*w.z; acc[0][3]+=h.x*w.w;
      acc[1][0]+=h.y*w.x; acc[1][1]+=h.y*w.y; acc[1][2]+=h.y*w.z; acc[1][3]+=h.y*w.w;
      acc[2][0]+=h.z*w.x; acc[2][1]+=h.z*w.y; acc[2][2]+=h.z*w.z; acc[2][3]+=h.z*w.w;
      acc[3][0]+=h.w*w.x; acc[3][1]+=h.w*w.y; acc[3][2]+=h.w*w.z; acc[3][3]+=h.w*w.w;
    }
    #pragma unroll
    for(int b=0;b<4;b++){
      float4 v; v.x=silu(acc[0][b]); v.y=silu(acc[1][b]); v.z=silu(acc[2][b]); v.w=silu(acc[3][b]);
      *(float4*)&sHB[(j0+b)*68+e0] = v;
    }
  }
  __syncthreads();
  {
    float acc[4][4];
    #pragma unroll
    for(int a=0;a<4;a++){ acc[a][0]=0;acc[a][1]=0;acc[a][2]=0;acc[a][3]=0; }
    for(int k=0;k<64;k++){
      float4 h = *(const float4*)&sHB[k*68+e0];
      float4 w = *(const float4*)&W3[k*64+j0];
      acc[0][0]+=h.x*w.x; acc[0][1]+=h.x*w.y; acc[0][2]+=h.x*w.z; acc[0][3]+=h.x*w.w;
      acc[1][0]+=h.y*w.x; acc[1][1]+=h.y*w.y; acc[1][2]+=h.y*w.z; acc[1][3]+=h.y*w.w;
      acc[2][0]+=h.z*w.x; acc[2][1]+=h.z*w.y; acc[2][2]+=h.z*w.z; acc[2][3]+=h.z*w.w;
      acc[3][0]+=h.w*w.x; acc[3][1]+=h.w*w.y; acc[3][2]+=h.w*w.z; acc[3][3]+=h.w*w.w;
    }
    #pragma unroll
    for(int b=0;b<4;b++){
      float4 v; v.x=silu(acc[0][b]); v.y=silu(acc[1][b]); v.z=silu(acc[2][b]); v.w=silu(acc[3][b]);
      *(float4*)&sHA[(j0+b)*68+e0] = v;
    }
  }
  __syncthreads();
  {
    int cc0 = (t&63)*4, g = t>>6;
    float acc[4][4][4];
    #pragma unroll
    for(int r=0;r<4;r++)
      #pragma unroll
      for(int a=0;a<4;a++){ acc[r][a][0]=0;acc[r][a][1]=0;acc[r][a][2]=0;acc[r][a][3]=0; }
    for(int k=0;k<64;k++){
      float4 w = *(const float4*)&W4[k*256+cc0];
      #pragma unroll
      for(int r=0;r<4;r++){
        float4 h = *(const float4*)&sHA[k*68 + (g+4*r)*4];
        acc[r][0][0]+=h.x*w.x; acc[r][0][1]+=h.x*w.y; acc[r][0][2]+=h.x*w.z; acc[r][0][3]+=h.x*w.w;
        acc[r][1][0]+=h.y*w.x; acc[r][1][1]+=h.y*w.y; acc[r][1][2]+=h.y*w.z; acc[r][1][3]+=h.y*w.w;
        acc[r][2][0]+=h.z*w.x; acc[r][2][1]+=h.z*w.y; acc[r][2][2]+=h.z*w.z; acc[r][2][3]+=h.z*w.w;
        acc[r][3][0]+=h.w*w.x; acc[r][3][1]+=h.w*w.y; acc[r][3][2]+=h.w*w.z; acc[r][3][3]+=h.w*w.w;
      }
    }
    #pragma unroll
    for(int r=0;r<4;r++)
      #pragma unroll
      for(int a=0;a<4;a++){
        int e = (g+4*r)*4 + a;
        float4 v; v.x=acc[r][a][0]; v.y=acc[r][a][1]; v.z=acc[r][a][2]; v.w=acc[r][a][3];
        *(float4*)&mix[(size_t)(be+e)*256 + cc0] = v;
      }
  }
}

// ---------- CSR build ----------
__global__ void k_zero(int* cnt){ int t=blockIdx.x*256+threadIdx.x; if(t<NN) cnt[t]=0; }
__global__ void k_count(const int* __restrict__ recv, int* cnt, int* pos){
  int e=blockIdx.x*256+threadIdx.x; pos[e]=atomicAdd(&cnt[recv[e]],1); }
__global__ __launch_bounds__(256) void k_scan(const int* __restrict__ cnt, int* __restrict__ off){
  __shared__ int sums[256]; __shared__ int bases[256];
  int t=threadIdx.x;
  int local[16]; int s=0;
  #pragma unroll
  for(int k=0;k<16;k++){ local[k]=cnt[t*16+k]; s+=local[k]; }
  sums[t]=s; __syncthreads();
  if(t==0){ int a=0; for(int q=0;q<256;q++){ bases[q]=a; a+=sums[q]; } }
  __syncthreads();
  int acc=bases[t];
  #pragma unroll
  for(int k=0;k<16;k++){ off[t*16+k]=acc; acc+=local[k]; }
  if(t==255) off[NN]=acc;
}
__global__ void k_fill(const int* __restrict__ recv, const int* __restrict__ off,
                       const int* __restrict__ pos, int* __restrict__ elist){
  int e=blockIdx.x*256+threadIdx.x; elist[off[recv[e]]+pos[e]]=e; }

// ---------- compact U3/U2/U1 ----------
__global__ __launch_bounds__(256) void k_compact(const float* __restrict__ U3,
    const float* __restrict__ U2, const float* __restrict__ U1,
    int* u3i, float* u3v, int* u2i, float* u2v, int* u1i, float* u1v, int* ucnt){
  const float* src; int n; int* oi; float* ov; int slot=blockIdx.x;
  if(slot==0){src=U3;n=16384;oi=u3i;ov=u3v;}
  else if(slot==1){src=U2;n=1024;oi=u2i;ov=u2v;}
  else {src=U1;n=64;oi=u1i;ov=u1v;}
  __shared__ int cnts[256]; __shared__ int bases[256];
  int t=threadIdx.x;
  int chunk=(n+255)/256;
  int lo=t*chunk, hi=min(n,lo+chunk); if(lo>n) lo=n;
  int c=0; for(int q=lo;q<hi;q++) if(src[q]!=0.f) c++;
  cnts[t]=c; __syncthreads();
  if(t==0){int a=0; for(int q=0;q<256;q++){bases[q]=a;a+=cnts[q];} }
  __syncthreads();
  int w=bases[t];
  for(int q=lo;q<hi;q++){ float v=src[q]; if(v!=0.f){ oi[w]=q; ov[w]=v; w++; } }
  __syncthreads();
  if(t==255) ucnt[slot]=w;
}

// ---------- edge gather: messages -> agg[n][1024] ----------
__global__ __launch_bounds__(256) void k_gather(
    const float* __restrict__ x, const float* __restrict__ mix,
    const float* __restrict__ Yp, const float* __restrict__ CG,
    const int* __restrict__ senders,
    const int* __restrict__ off, const int* __restrict__ elist,
    float* __restrict__ agg)
{
  __shared__ __align__(16) char smem[22528];
  float* sCG  = (float*)smem;            // [3840] phase1
  float* sMW  = (float*)(smem+15360);    // [4][256] phase1 (per-wave private)
  float* sP   = (float*)smem;            // [4096] phase2 alias over sCG+sMW
  int*   sEl  = (int*)(smem+19456);      // [256]
  int*   sEl2 = (int*)(smem+20480);      // [256]
  int*   sSnd = (int*)(smem+21504);      // [256]

  int n = blockIdx.x, t = threadIdx.x;
  int w = t>>6, l = t&63, lc = l&31, kh = (l>>5)*8;

  for (int k=t;k<3840;k+=256) sCG[k]=CG[k];
  int base = off[n];
  int deg = off[n+1]-base; if (deg>256) deg=256;
  for (int d=t; d<deg; d+=256) sEl[d]=elist[base+d];
  __syncthreads();
  // deterministic order: parallel rank sort (edge ids unique)
  for (int d=t; d<deg; d+=256){
    int v=sEl[d]; int r=0;
    for(int q=0;q<deg;q++) r += (sEl[q]<v);
    sEl2[r]=v;
  }
  __syncthreads();
  for (int d=t; d<deg; d+=256) sSnd[d]=senders[sEl2[d]];
  __syncthreads();

  float aggF[8], aggT[8];
  #pragma unroll
  for(int j=0;j<8;j++){ aggF[j]=0.f; aggT[j]=0.f; }

  // no barriers: sMW per-wave private; sEl2/sSnd/sCG read-only
  for (int g0=0; g0<deg; g0+=4){
    int d = g0+w;
    if (d<deg){
      int myE = sEl2[d];
      int snd = sSnd[d];
      float4 mixF = *(const float4*)&mix[(size_t)myE*256 + lc*4];
      float4 mixT = *(const float4*)&mix[(size_t)myE*256 + 128 + lc*4];
      float fsv[16];
      #pragma unroll
      for(int q=0;q<4;q++) *(float4*)&fsv[q*4] = *(const float4*)&x[(size_t)snd*512 + lc*16 + q*4];
      float yv[16];
      #pragma unroll
      for(int q=0;q<4;q++) *(float4*)&yv[q*4] = *(const float4*)&Yp[(size_t)myE*16+q*4];
      int li = l>>4, lk = l&15;
      #pragma unroll
      for(int r=0;r<4;r++){
        int i = r*4+li;
        float m=0.f;
        #pragma unroll
        for(int j=0;j<15;j++) m += yv[j]*sCG[i*240 + j*16 + lk];
        sMW[w*256 + r*64 + l] = m;
      }
      float tp[8];
      #pragma unroll
      for(int j=0;j<8;j++) tp[j]=0.f;
      #pragma unroll
      for(int i=0;i<16;i++){
        float4 ma = *(const float4*)&sMW[w*256 + i*16 + kh];
        float4 mb = *(const float4*)&sMW[w*256 + i*16 + kh + 4];
        float f = fsv[i];
        tp[0]+=f*ma.x; tp[1]+=f*ma.y; tp[2]+=f*ma.z; tp[3]+=f*ma.w;
        tp[4]+=f*mb.x; tp[5]+=f*mb.y; tp[6]+=f*mb.z; tp[7]+=f*mb.w;
      }
      #pragma unroll
      for(int j=0;j<8;j++){
        int k = kh+j;
        int g = l_of(k);
        float mF = (g==0)?mixF.x:(g==1)?mixF.y:(g==2)?mixF.z:mixF.w;
        float mT = (g==0)?mixT.x:(g==1)?mixT.y:(g==2)?mixT.z:mixT.w;
        aggF[j] += fsv[k]*mF;
        aggT[j] += tp[j]*mT;
      }
    }
  }
  __syncthreads();   // all waves done with sCG/sMW before aliasing

  #pragma unroll
  for(int j=0;j<8;j++){
    sP[w*1024 + lc*16 + kh + j]       = aggF[j];
    sP[w*1024 + (32+lc)*16 + kh + j]  = aggT[j];
  }
  __syncthreads();
  for (int idx=t; idx<1024; idx+=256)
    agg[(size_t)n*1024 + idx] = sP[idx]+sP[1024+idx]+sP[2048+idx]+sP[3072+idx];
}

// ---------- tail: Wdown + sparse contraction + output ----------
__global__ __launch_bounds__(256) void k_tail(
    const float* __restrict__ agg, const float* __restrict__ x,
    const float* __restrict__ Wdown,
    const int* __restrict__ u3i, const float* __restrict__ u3v,
    const int* __restrict__ u2i, const float* __restrict__ u2v,
    const int* __restrict__ u1i, const float* __restrict__ u1v,
    const int* __restrict__ ucnt,
    const float* __restrict__ w3, const float* __restrict__ w2,
    const float* __restrict__ w1,
    const float* __restrict__ Wsc, const float* __restrict__ Wout,
    const int* __restrict__ species,
    float* __restrict__ out)
{
  __shared__ float sAgg[1024];
  __shared__ float sy[512];      // [i][c]: i*32+c
  __shared__ float sPart[1024];  // (i*8+p)*32+c
  __shared__ float sB[128];
  __shared__ float sXn[512];

  int n = blockIdx.x, t = threadIdx.x;
  #pragma unroll
  for(int q=0;q<4;q++) sAgg[q*256+t] = agg[(size_t)n*1024 + q*256 + t];
  sXn[t]     = x[(size_t)n*512 + t];
  sXn[256+t] = x[(size_t)n*512 + 256 + t];
  __syncthreads();

  // y[f][i] = (1/16) sum_c agg[c][i] Wdown[l(i)][c][f]   -> sy[i*32+f]
  #pragma unroll
  for(int q=0;q<2;q++){
    int idx=q*256+t;
    int i=idx>>5, f=idx&31;
    const float* W = Wdown + l_of(i)*64*32;
    float a=0.f;
    for(int c=0;c<64;c++) a += sAgg[c*16+i]*W[c*32+f];
    sy[i*32+f]=a*0.0625f;
  }
  __syncthreads();

  int spec = species[n];
  {
    int c = t&31, p = t>>5;
    float w30=w3[spec*64+c], w31=w3[spec*64+32+c];
    float w20=w2[spec*64+c], w21=w2[spec*64+32+c];
    float w10=w1[spec*64+c], w11=w1[spec*64+32+c];
    float r0=0.f,r1=0.f,r2=0.f,r3=0.f;
    int n3=ucnt[0], n2=ucnt[1], n1=ucnt[2];
    for(int q=p;q<n3;q+=8){
      int id=u3i[q]; float v=u3v[q];
      int i=id&3, j=(id>>2)&15, b=(id>>6)&15, a=(id>>10)&15;
      float term = v*sy[a*32+c]*sy[b*32+c]*sy[j*32+c]*((i==0)?w30:w31);
      if(i==0) r0+=term; else if(i==1) r1+=term; else if(i==2) r2+=term; else r3+=term;
    }
    for(int q=p;q<n2;q+=8){
      int id=u2i[q]; float v=u2v[q];
      int i=id&3, b=(id>>2)&15, a=(id>>6)&15;
      float term = v*sy[a*32+c]*sy[b*32+c]*((i==0)?w20:w21);
      if(i==0) r0+=term; else if(i==1) r1+=term; else if(i==2) r2+=term; else r3+=term;
    }
    for(int q=p;q<n1;q+=8){
      int id=u1i[q]; float v=u1v[q];
      int i=id&3, a=(id>>2)&15;
      float term = v*sy[a*32+c]*((i==0)?w10:w11);
      if(i==0) r0+=term; else if(i==1) r1+=term; else if(i==2) r2+=term; else r3+=term;
    }
    sPart[(0*8+p)*32+c]=r0;
    sPart[(1*8+p)*32+c]=r1;
    sPart[(2*8+p)*32+c]=r2;
    sPart[(3*8+p)*32+c]=r3;
  }
  __syncthreads();
  if (t<128){
    int i=t>>5, c=t&31;
    float a=0.f;
    #pragma unroll
    for(int p=0;p<8;p++) a += sPart[(i*8+p)*32+c];
    sB[c*4+i]=a;
  }
  __syncthreads();
  if (t<128){
    int f=t>>2, i=t&3;
    int sel = (i==0)?0:1;
    const float* Wo = Wout + sel*1024;
    const float* Ws = Wsc + (size_t)(sel*64+spec)*1024;
    float o=0.f, sc=0.f;
    for(int c=0;c<32;c++){
      o  += sB[c*4+i]*Wo[c*32+f];
      sc += sXn[c*16+i]*Ws[c*32+f];
    }
    out[(size_t)n*128 + f*4 + i] = o + sc;
  }
}

extern "C" void kernel_launch(void* const* d_in, const int* in_sizes, int n_in,
                              void* d_out, int out_size, void* d_ws, size_t ws_size,
                              hipStream_t stream){
  (void)in_sizes; (void)n_in; (void)out_size; (void)ws_size;
  const float* feats = (const float*)d_in[0];
  const float* vec   = (const float*)d_in[1];
  const float* rad   = (const float*)d_in[2];
  const float* Wup   = (const float*)d_in[3];
  const float* CG    = (const float*)d_in[4];
  const float* Wr1   = (const float*)d_in[5];
  const float* Wr2   = (const float*)d_in[6];
  const float* Wr3   = (const float*)d_in[7];
  const float* Wr4   = (const float*)d_in[8];
  const float* Wdown = (const float*)d_in[9];
  const float* U3    = (const float*)d_in[10];
  const float* U2    = (const float*)d_in[11];
  const float* U1    = (const float*)d_in[12];
  const float* w3    = (const float*)d_in[13];
  const float* w2    = (const float*)d_in[14];
  const float* w1    = (const float*)d_in[15];
  const float* Wsc   = (const float*)d_in[16];
  const float* Wout  = (const float*)d_in[17];
  const int* species = (const int*)d_in[18];
  const int* senders = (const int*)d_in[19];
  const int* recv    = (const int*)d_in[20];
  float* out = (float*)d_out;

  char* w = (char*)d_ws;
  float* x    = (float*)w;  w += (size_t)NN*512*4;
  float* mix  = (float*)w;  w += (size_t)EE*256*4;
  float* Yp   = (float*)w;  w += (size_t)EE*16*4;
  float* agg  = (float*)w;  w += (size_t)NN*1024*4;
  int* cnt    = (int*)w;    w += (size_t)NN*4;
  int* off    = (int*)w;    w += (size_t)(NN+1)*4;
  int* pos    = (int*)w;    w += (size_t)EE*4;
  int* elist  = (int*)w;    w += (size_t)EE*4;
  int* u3i    = (int*)w;    w += 16384*4;
  float* u3v  = (float*)w;  w += 16384*4;
  int* u2i    = (int*)w;    w += 1024*4;
  float* u2v  = (float*)w;  w += 1024*4;
  int* u1i    = (int*)w;    w += 64*4;
  float* u1v  = (float*)w;  w += 64*4;
  int* ucnt   = (int*)w;    w += 16;

  k_compact<<<3,256,0,stream>>>(U3,U2,U1,u3i,u3v,u2i,u2v,u1i,u1v,ucnt);
  k_x<<<NN,512,0,stream>>>(feats,Wup,x);
  k_Y<<<EE/256,256,0,stream>>>(vec,Yp);
  k_mix<<<EE/64,256,0,stream>>>(rad,Wr1,Wr2,Wr3,Wr4,mix);
  k_zero<<<NN/256,256,0,stream>>>(cnt);
  k_count<<<EE/256,256,0,stream>>>(recv,cnt,pos);
  k_scan<<<1,256,0,stream>>>(cnt,off);
  k_fill<<<EE/256,256,0,stream>>>(recv,off,pos,elist);
  k_gather<<<NN,256,0,stream>>>(x,mix,Yp,CG,senders,off,elist,agg);
  k_tail<<<NN,256,0,stream>>>(agg,x,Wdown,u3i,u3v,u2i,u2v,u1i,u1v,ucnt,
                              w3,w2,w1,Wsc,Wout,species,out);
}

// Round 5
// 315.367 us; speedup vs baseline: 1.1747x; 1.1747x over previous
//
#include <hip/hip_runtime.h>
#include <math.h>

#define NN 4096
#define FF 32
#define DD 16
#define EE 65536

__device__ __forceinline__ int l_of(int i){ return (i==0)?0:(i<4)?1:(i<9)?2:3; }
__device__ __forceinline__ float silu(float v){ return v/(1.f+expf(-v)); }

// ---------- x = per_l_linear(node_feats, W_up) ----------
__global__ __launch_bounds__(512) void k_x(const float* __restrict__ feats,
        const float* __restrict__ Wup, float* __restrict__ x){
  __shared__ float sF[FF*DD];
  __shared__ float sW[4*FF*FF];
  int n = blockIdx.x, t = threadIdx.x;
  sF[t] = feats[(size_t)n*FF*DD + t];
  for (int k=t;k<4*FF*FF;k+=512) sW[k]=Wup[k];
  __syncthreads();
  int f = t>>4, i = t&15;
  const float* W = &sW[l_of(i)*FF*FF];
  float a=0.f;
  #pragma unroll
  for (int c=0;c<FF;c++) a += sF[c*DD+i]*W[c*FF+f];
  x[(size_t)n*FF*DD + t] = a;
}

// ---------- spherical harmonics (edge-parallel) ----------
__global__ __launch_bounds__(256) void k_Y(const float* __restrict__ vec, float* __restrict__ Yp){
  int e = blockIdx.x*256+threadIdx.x;
  if (e>=EE) return;
  float vx=vec[(size_t)e*3+0], vy=vec[(size_t)e*3+1], vz=vec[(size_t)e*3+2];
  float r2=vx*vx+vy*vy+vz*vz;
  float inv = (r2==0.f)?1.f:rsqrtf(r2);
  float X=vx*inv, Y=vy*inv, Z=vz*inv;
  const float s3=1.7320508075688772f, s5=2.23606797749979f, s7=2.6457513110645907f;
  const float s15=3.872983346207417f, s42=6.48074069840786f, s70=8.366600265340756f, s105=10.246950765959598f;
  float y[16];
  y[0]=s3*X; y[1]=s3*Y; y[2]=s3*Z;
  y[3]=s15*X*Y; y[4]=s15*Y*Z; y[5]=0.5f*s5*(3.f*Z*Z-1.f); y[6]=s15*X*Z; y[7]=0.5f*s15*(X*X-Y*Y);
  y[8]=0.25f*s70*Y*(3.f*X*X-Y*Y); y[9]=s105*X*Y*Z; y[10]=0.25f*s42*Y*(5.f*Z*Z-1.f);
  y[11]=0.5f*s7*Z*(5.f*Z*Z-3.f); y[12]=0.25f*s42*X*(5.f*Z*Z-1.f);
  y[13]=0.5f*s105*Z*(X*X-Y*Y); y[14]=0.25f*s70*X*(X*X-3.f*Y*Y);
  y[15]=0.f;
  #pragma unroll
  for(int q=0;q<4;q++) *(float4*)&Yp[(size_t)e*16+q*4] = *(float4*)&y[q*4];
}

// ---------- radial MLP -> mix (E, 64, 4) ----------
__global__ __launch_bounds__(256) void k_mix(const float* __restrict__ rad,
    const float* __restrict__ W1, const float* __restrict__ W2,
    const float* __restrict__ W3, const float* __restrict__ W4,
    float* __restrict__ mix){
  __shared__ float sRadT[8*68];
  __shared__ float sW1[8*64];
  __shared__ float sHA[64*68];
  __shared__ float sHB[64*68];
  int t = threadIdx.x;
  int be = blockIdx.x*64;
  for (int k=t;k<8*64;k+=256) sW1[k]=W1[k];
  for (int idx=t; idx<64*8; idx+=256){ int e=idx>>3, k=idx&7; sRadT[k*68+e]=rad[(size_t)(be+e)*8+k]; }
  __syncthreads();
  int e0 = (t>>4)*4, j0 = (t&15)*4;
  {
    float acc[4][4];
    #pragma unroll
    for(int a=0;a<4;a++){ acc[a][0]=0;acc[a][1]=0;acc[a][2]=0;acc[a][3]=0; }
    #pragma unroll
    for(int k=0;k<8;k++){
      float4 h = *(const float4*)&sRadT[k*68+e0];
      float4 w = *(const float4*)&sW1[k*64+j0];
      acc[0][0]+=h.x*w.x; acc[0][1]+=h.x*w.y; acc[0][2]+=h.x*w.z; acc[0][3]+=h.x*w.w;
      acc[1][0]+=h.y*w.x; acc[1][1]+=h.y*w.y; acc[1][2]+=h.y*w.z; acc[1][3]+=h.y*w.w;
      acc[2][0]+=h.z*w.x; acc[2][1]+=h.z*w.y; acc[2][2]+=h.z*w.z; acc[2][3]+=h.z*w.w;
      acc[3][0]+=h.w*w.x; acc[3][1]+=h.w*w.y; acc[3][2]+=h.w*w.z; acc[3][3]+=h.w*w.w;
    }
    #pragma unroll
    for(int b=0;b<4;b++){
      float4 v; v.x=silu(acc[0][b]); v.y=silu(acc[1][b]); v.z=silu(acc[2][b]); v.w=silu(acc[3][b]);
      *(float4*)&sHA[(j0+b)*68+e0] = v;
    }
  }
  __syncthreads();
  {
    float acc[4][4];
    #pragma unroll
    for(int a=0;a<4;a++){ acc[a][0]=0;acc[a][1]=0;acc[a][2]=0;acc[a][3]=0; }
    for(int k=0;k<64;k++){
      float4 h = *(const float4*)&sHA[k*68+e0];
      float4 w = *(const float4*)&W2[k*64+j0];
      acc[0][0]+=h.x*w.x; acc[0][1]+=h.x*w.y; acc[0][2]+=h.x*w.z; acc[0][3]+=h.x*w.w;
      acc[1][0]+=h.y*w.x; acc[1][1]+=h.y*w.y; acc[1][2]+=h.y*w.z; acc[1][3]+=h.y*w.w;
      acc[2][0]+=h.z*w.x; acc[2][1]+=h.z*w.y; acc[2][2]+=h.z*w.z; acc[2][3]+=h.z*w.w;
      acc[3][0]+=h.w*w.x; acc[3][1]+=h.w*w.y; acc[3][2]+=h.w*w.z; acc[3][3]+=h.w*w.w;
    }
    #pragma unroll
    for(int b=0;b<4;b++){
      float4 v; v.x=silu(acc[0][b]); v.y=silu(acc[1][b]); v.z=silu(acc[2][b]); v.w=silu(acc[3][b]);
      *(float4*)&sHB[(j0+b)*68+e0] = v;
    }
  }
  __syncthreads();
  {
    float acc[4][4];
    #pragma unroll
    for(int a=0;a<4;a++){ acc[a][0]=0;acc[a][1]=0;acc[a][2]=0;acc[a][3]=0; }
    for(int k=0;k<64;k++){
      float4 h = *(const float4*)&sHB[k*68+e0];
      float4 w = *(const float4*)&W3[k*64+j0];
      acc[0][0]+=h.x*w.x; acc[0][1]+=h.x*w.y; acc[0][2]+=h.x*w.z; acc[0][3]+=h.x*w.w;
      acc[1][0]+=h.y*w.x; acc[1][1]+=h.y*w.y; acc[1][2]+=h.y*w.z; acc[1][3]+=h.y*w.w;
      acc[2][0]+=h.z*w.x; acc[2][1]+=h.z*w.y; acc[2][2]+=h.z*w.z; acc[2][3]+=h.z*w.w;
      acc[3][0]+=h.w*w.x; acc[3][1]+=h.w*w.y; acc[3][2]+=h.w*w.z; acc[3][3]+=h.w*w.w;
    }
    #pragma unroll
    for(int b=0;b<4;b++){
      float4 v; v.x=silu(acc[0][b]); v.y=silu(acc[1][b]); v.z=silu(acc[2][b]); v.w=silu(acc[3][b]);
      *(float4*)&sHA[(j0+b)*68+e0] = v;
    }
  }
  __syncthreads();
  {
    int cc0 = (t&63)*4, g = t>>6;
    float acc[4][4][4];
    #pragma unroll
    for(int r=0;r<4;r++)
      #pragma unroll
      for(int a=0;a<4;a++){ acc[r][a][0]=0;acc[r][a][1]=0;acc[r][a][2]=0;acc[r][a][3]=0; }
    for(int k=0;k<64;k++){
      float4 w = *(const float4*)&W4[k*256+cc0];
      #pragma unroll
      for(int r=0;r<4;r++){
        float4 h = *(const float4*)&sHA[k*68 + (g+4*r)*4];
        acc[r][0][0]+=h.x*w.x; acc[r][0][1]+=h.x*w.y; acc[r][0][2]+=h.x*w.z; acc[r][0][3]+=h.x*w.w;
        acc[r][1][0]+=h.y*w.x; acc[r][1][1]+=h.y*w.y; acc[r][1][2]+=h.y*w.z; acc[r][1][3]+=h.y*w.w;
        acc[r][2][0]+=h.z*w.x; acc[r][2][1]+=h.z*w.y; acc[r][2][2]+=h.z*w.z; acc[r][2][3]+=h.z*w.w;
        acc[r][3][0]+=h.w*w.x; acc[r][3][1]+=h.w*w.y; acc[r][3][2]+=h.w*w.z; acc[r][3][3]+=h.w*w.w;
      }
    }
    #pragma unroll
    for(int r=0;r<4;r++)
      #pragma unroll
      for(int a=0;a<4;a++){
        int e = (g+4*r)*4 + a;
        float4 v; v.x=acc[r][a][0]; v.y=acc[r][a][1]; v.z=acc[r][a][2]; v.w=acc[r][a][3];
        *(float4*)&mix[(size_t)(be+e)*256 + cc0] = v;
      }
  }
}

// ---------- CSR build ----------
__global__ void k_zero(int* cnt){ int t=blockIdx.x*256+threadIdx.x; if(t<NN) cnt[t]=0; }
__global__ void k_count(const int* __restrict__ recv, int* cnt, int* pos){
  int e=blockIdx.x*256+threadIdx.x; pos[e]=atomicAdd(&cnt[recv[e]],1); }
__global__ __launch_bounds__(256) void k_scan(const int* __restrict__ cnt, int* __restrict__ off){
  __shared__ int sums[256]; __shared__ int bases[256];
  int t=threadIdx.x;
  int local[16]; int s=0;
  #pragma unroll
  for(int k=0;k<16;k++){ local[k]=cnt[t*16+k]; s+=local[k]; }
  sums[t]=s; __syncthreads();
  if(t==0){ int a=0; for(int q=0;q<256;q++){ bases[q]=a; a+=sums[q]; } }
  __syncthreads();
  int acc=bases[t];
  #pragma unroll
  for(int k=0;k<16;k++){ off[t*16+k]=acc; acc+=local[k]; }
  if(t==255) off[NN]=acc;
}
__global__ void k_fill(const int* __restrict__ recv, const int* __restrict__ off,
                       const int* __restrict__ pos, int* __restrict__ elist){
  int e=blockIdx.x*256+threadIdx.x; elist[off[recv[e]]+pos[e]]=e; }

// ---------- compact U3/U2/U1 into per-i sorted lists ----------
__global__ __launch_bounds__(256) void k_compact(const float* __restrict__ U3,
    const float* __restrict__ U2, const float* __restrict__ U1,
    int* u3i, float* u3v, int* u2i, float* u2v, int* u1i, float* u1v, int* uoff){
  const float* src; int n; int* oi; float* ov; int slot=blockIdx.x;
  if(slot==0){src=U3;n=16384;oi=u3i;ov=u3v;}
  else if(slot==1){src=U2;n=1024;oi=u2i;ov=u2v;}
  else {src=U1;n=64;oi=u1i;ov=u1v;}
  __shared__ int cnts[256][4]; __shared__ int bases[256][4];
  int t=threadIdx.x;
  int chunk=(n+255)/256;
  int lo=t*chunk, hi=min(n,lo+chunk); if(lo>n) lo=n;
  int c0=0,c1=0,c2=0,c3=0;
  for(int q=lo;q<hi;q++) if(src[q]!=0.f){
    int i=q&3;
    if(i==0)c0++; else if(i==1)c1++; else if(i==2)c2++; else c3++;
  }
  cnts[t][0]=c0; cnts[t][1]=c1; cnts[t][2]=c2; cnts[t][3]=c3;
  __syncthreads();
  if(t==0){
    int a=0;
    for(int i=0;i<4;i++){ uoff[slot*5+i]=a;
      for(int q=0;q<256;q++){ bases[q][i]=a; a+=cnts[q][i]; } }
    uoff[slot*5+4]=a;
  }
  __syncthreads();
  int w0=bases[t][0], w1_=bases[t][1], w2_=bases[t][2], w3_=bases[t][3];
  for(int q=lo;q<hi;q++){ float v=src[q]; if(v!=0.f){
    int i=q&3;
    if(i==0){ oi[w0]=q; ov[w0]=v; w0++; }
    else if(i==1){ oi[w1_]=q; ov[w1_]=v; w1_++; }
    else if(i==2){ oi[w2_]=q; ov[w2_]=v; w2_++; }
    else { oi[w3_]=q; ov[w3_]=v; w3_++; }
  } }
}

// ---------- edge gather: messages -> agg[n][1024] ----------
__global__ __launch_bounds__(256) void k_gather(
    const float* __restrict__ x, const float* __restrict__ mix,
    const float* __restrict__ Yp, const float* __restrict__ CG,
    const int* __restrict__ senders,
    const int* __restrict__ off, const int* __restrict__ elist,
    float* __restrict__ agg)
{
  __shared__ __align__(16) char smem[22528];
  float* sCG  = (float*)smem;            // [3840] phase1
  float* sMW  = (float*)(smem+15360);    // [4][256] phase1 (per-wave private)
  float* sP   = (float*)smem;            // [4096] phase2 alias over sCG+sMW
  int*   sEl  = (int*)(smem+19456);      // [256]
  int*   sEl2 = (int*)(smem+20480);      // [256]
  int*   sSnd = (int*)(smem+21504);      // [256]

  int n = blockIdx.x, t = threadIdx.x;
  int w = t>>6, l = t&63, lc = l&31, kh = (l>>5)*8;

  for (int k=t;k<3840;k+=256) sCG[k]=CG[k];
  int base = off[n];
  int deg = off[n+1]-base; if (deg>256) deg=256;
  for (int d=t; d<deg; d+=256) sEl[d]=elist[base+d];
  __syncthreads();
  // deterministic order: parallel rank sort (edge ids unique)
  for (int d=t; d<deg; d+=256){
    int v=sEl[d]; int r=0;
    for(int q=0;q<deg;q++) r += (sEl[q]<v);
    sEl2[r]=v;
  }
  __syncthreads();
  for (int d=t; d<deg; d+=256) sSnd[d]=senders[sEl2[d]];
  __syncthreads();

  float aggF[8], aggT[8];
  #pragma unroll
  for(int j=0;j<8;j++){ aggF[j]=0.f; aggT[j]=0.f; }

  // no barriers: sMW per-wave private; sEl2/sSnd/sCG read-only
  for (int g0=0; g0<deg; g0+=4){
    int d = g0+w;
    if (d<deg){
      int myE = __builtin_amdgcn_readfirstlane(sEl2[d]);
      int snd = __builtin_amdgcn_readfirstlane(sSnd[d]);
      const float* yrow = Yp + (size_t)myE*16;     // uniform -> s_load
      const float* mrow = mix + (size_t)myE*256;   // uniform base
      const float* xrow = x + (size_t)snd*512;     // uniform base
      float yv[16];
      #pragma unroll
      for(int q=0;q<4;q++) *(float4*)&yv[q*4] = *(const float4*)&yrow[q*4];
      float4 mixF = *(const float4*)&mrow[lc*4];
      float4 mixT = *(const float4*)&mrow[128 + lc*4];
      float fsv[16];
      #pragma unroll
      for(int q=0;q<4;q++) *(float4*)&fsv[q*4] = *(const float4*)&xrow[lc*16 + q*4];
      int li = l>>4, lk = l&15;
      #pragma unroll
      for(int r=0;r<4;r++){
        int i = r*4+li;
        float m=0.f;
        #pragma unroll
        for(int j=0;j<15;j++) m += yv[j]*sCG[i*240 + j*16 + lk];
        sMW[w*256 + r*64 + l] = m;
      }
      float tp[8];
      #pragma unroll
      for(int j=0;j<8;j++) tp[j]=0.f;
      #pragma unroll
      for(int i=0;i<16;i++){
        float4 ma = *(const float4*)&sMW[w*256 + i*16 + kh];
        float4 mb = *(const float4*)&sMW[w*256 + i*16 + kh + 4];
        float f = fsv[i];
        tp[0]+=f*ma.x; tp[1]+=f*ma.y; tp[2]+=f*ma.z; tp[3]+=f*ma.w;
        tp[4]+=f*mb.x; tp[5]+=f*mb.y; tp[6]+=f*mb.z; tp[7]+=f*mb.w;
      }
      #pragma unroll
      for(int j=0;j<8;j++){
        int k = kh+j;
        int g = l_of(k);
        float mF = (g==0)?mixF.x:(g==1)?mixF.y:(g==2)?mixF.z:mixF.w;
        float mT = (g==0)?mixT.x:(g==1)?mixT.y:(g==2)?mixT.z:mixT.w;
        aggF[j] += fsv[k]*mF;
        aggT[j] += tp[j]*mT;
      }
    }
  }
  __syncthreads();   // all waves done with sCG/sMW before aliasing

  #pragma unroll
  for(int j=0;j<8;j++){
    sP[w*1024 + lc*16 + kh + j]       = aggF[j];
    sP[w*1024 + (32+lc)*16 + kh + j]  = aggT[j];
  }
  __syncthreads();
  for (int idx=t; idx<1024; idx+=256)
    agg[(size_t)n*1024 + idx] = sP[idx]+sP[1024+idx]+sP[2048+idx]+sP[3072+idx];
}

// ---------- tail: Wdown + sparse contraction + output (2 nodes/block) ----------
__global__ __launch_bounds__(256) void k_tail(
    const float* __restrict__ agg, const float* __restrict__ x,
    const float* __restrict__ Wdown,
    const int* __restrict__ u3i, const float* __restrict__ u3v,
    const int* __restrict__ u2i, const float* __restrict__ u2v,
    const int* __restrict__ u1i, const float* __restrict__ u1v,
    const int* __restrict__ uoff,
    const float* __restrict__ w3, const float* __restrict__ w2,
    const float* __restrict__ w1,
    const float* __restrict__ Wsc, const float* __restrict__ Wout,
    const int* __restrict__ species,
    float* __restrict__ out)
{
  __shared__ float sAgg[2048];   // phase1: agg[2][1024]; phase2 alias: sXn[1024]+sB[256]
  __shared__ float sy[1024];     // [half][i][c] : half*512 + i*32 + c
  __shared__ float sPart[1024];  // [p][i][half*32+c]

  int n0 = blockIdx.x*2, t = threadIdx.x;
  #pragma unroll
  for(int q=0;q<8;q++) sAgg[q*256+t] = agg[(size_t)n0*1024 + q*256 + t];
  __syncthreads();

  // Wdown: thread -> (h, i, f0..f0+3); sy[h][i][f] = (1/16) sum_c agg[h][c][i] W[l(i)][c][f]
  {
    int h=t>>7, ii=(t>>3)&15, f0=(t&7)*4;
    const float* W = Wdown + l_of(ii)*2048;
    float ax=0.f, ay=0.f, az=0.f, aw=0.f;
    for(int c=0;c<64;c++){
      float a = sAgg[h*1024 + c*16 + ii];
      float4 wv = *(const float4*)&W[c*32+f0];
      ax+=a*wv.x; ay+=a*wv.y; az+=a*wv.z; aw+=a*wv.w;
    }
    sy[h*512 + ii*32 + f0+0]=ax*0.0625f;
    sy[h*512 + ii*32 + f0+1]=ay*0.0625f;
    sy[h*512 + ii*32 + f0+2]=az*0.0625f;
    sy[h*512 + ii*32 + f0+3]=aw*0.0625f;
  }
  __syncthreads();   // sAgg reads done; sy visible

  float* sXn = sAgg;          // [half][512]
  float* sB  = sAgg + 1024;   // [half][128]
  #pragma unroll
  for(int q=0;q<4;q++){ int idx=q*256+t;
    sXn[idx] = x[(size_t)(n0+(idx>>9))*512 + (idx&511)]; }

  // sparse contraction: wave-uniform term stream (scalar loads), half-wave per node
  {
    int p  = __builtin_amdgcn_readfirstlane(t>>6);  // wave id = stream
    int c  = t&31, hf=(t>>5)&1;
    int spec = species[n0+hf];
    const float* syc = &sy[hf*512 + c];
    #pragma unroll
    for(int i=0;i<4;i++){
      float r3=0.f;
      for(int q=uoff[i]+p; q<uoff[i+1]; q+=4){
        int id=u3i[q]; float v=u3v[q];
        int a=(id>>10)&15, b=(id>>6)&15, j=(id>>2)&15;
        r3 += v*syc[a*32]*syc[b*32]*syc[j*32];
      }
      float r2=0.f;
      for(int q=uoff[5+i]+p; q<uoff[5+i+1]; q+=4){
        int id=u2i[q]; float v=u2v[q];
        int a=(id>>6)&15, b=(id>>2)&15;
        r2 += v*syc[a*32]*syc[b*32];
      }
      float r1=0.f;
      for(int q=uoff[10+i]+p; q<uoff[10+i+1]; q+=4){
        int id=u1i[q]; float v=u1v[q];
        int a=(id>>2)&15;
        r1 += v*syc[a*32];
      }
      float wa = (i==0)? w3[spec*64+c] : w3[spec*64+32+c];
      float wb = (i==0)? w2[spec*64+c] : w2[spec*64+32+c];
      float wc = (i==0)? w1[spec*64+c] : w1[spec*64+32+c];
      sPart[p*256 + i*64 + hf*32 + c] = r3*wa + r2*wb + r1*wc;
    }
  }
  __syncthreads();

  // reduce over 4 streams -> sB[half][c*4+i]
  {
    int hf2=t>>7, c2=(t>>2)&31, i2=t&3;
    int o = i2*64 + hf2*32 + c2;
    sB[hf2*128 + c2*4 + i2] = sPart[o] + sPart[256+o] + sPart[512+o] + sPart[768+o];
  }
  __syncthreads();

  // output: thread -> (half, f, i)
  {
    int hf3=t>>7, f=(t>>2)&31, i3=t&3;
    int sp2 = species[n0+hf3];
    int sel = (i3==0)?0:1;
    const float* Wo = Wout + sel*1024;
    const float* Ws = Wsc + (size_t)(sel*64+sp2)*1024;
    float o=0.f, sc=0.f;
    for(int c2=0;c2<32;c2++){
      o  += sB[hf3*128 + c2*4 + i3]*Wo[c2*32+f];
      sc += sXn[hf3*512 + c2*16 + i3]*Ws[c2*32+f];
    }
    out[(size_t)(n0+hf3)*128 + f*4 + i3] = o + sc;
  }
}

extern "C" void kernel_launch(void* const* d_in, const int* in_sizes, int n_in,
                              void* d_out, int out_size, void* d_ws, size_t ws_size,
                              hipStream_t stream){
  (void)in_sizes; (void)n_in; (void)out_size; (void)ws_size;
  const float* feats = (const float*)d_in[0];
  const float* vec   = (const float*)d_in[1];
  const float* rad   = (const float*)d_in[2];
  const float* Wup   = (const float*)d_in[3];
  const float* CG    = (const float*)d_in[4];
  const float* Wr1   = (const float*)d_in[5];
  const float* Wr2   = (const float*)d_in[6];
  const float* Wr3   = (const float*)d_in[7];
  const float* Wr4   = (const float*)d_in[8];
  const float* Wdown = (const float*)d_in[9];
  const float* U3    = (const float*)d_in[10];
  const float* U2    = (const float*)d_in[11];
  const float* U1    = (const float*)d_in[12];
  const float* w3    = (const float*)d_in[13];
  const float* w2    = (const float*)d_in[14];
  const float* w1    = (const float*)d_in[15];
  const float* Wsc   = (const float*)d_in[16];
  const float* Wout  = (const float*)d_in[17];
  const int* species = (const int*)d_in[18];
  const int* senders = (const int*)d_in[19];
  const int* recv    = (const int*)d_in[20];
  float* out = (float*)d_out;

  char* w = (char*)d_ws;
  float* x    = (float*)w;  w += (size_t)NN*512*4;
  float* mix  = (float*)w;  w += (size_t)EE*256*4;
  float* Yp   = (float*)w;  w += (size_t)EE*16*4;
  float* agg  = (float*)w;  w += (size_t)NN*1024*4;
  int* cnt    = (int*)w;    w += (size_t)NN*4;
  int* off    = (int*)w;    w += (size_t)(NN+1)*4;
  int* pos    = (int*)w;    w += (size_t)EE*4;
  int* elist  = (int*)w;    w += (size_t)EE*4;
  int* u3i    = (int*)w;    w += 16384*4;
  float* u3v  = (float*)w;  w += 16384*4;
  int* u2i    = (int*)w;    w += 1024*4;
  float* u2v  = (float*)w;  w += 1024*4;
  int* u1i    = (int*)w;    w += 64*4;
  float* u1v  = (float*)w;  w += 64*4;
  int* uoff   = (int*)w;    w += 16*4;

  k_compact<<<3,256,0,stream>>>(U3,U2,U1,u3i,u3v,u2i,u2v,u1i,u1v,uoff);
  k_x<<<NN,512,0,stream>>>(feats,Wup,x);
  k_Y<<<EE/256,256,0,stream>>>(vec,Yp);
  k_mix<<<EE/64,256,0,stream>>>(rad,Wr1,Wr2,Wr3,Wr4,mix);
  k_zero<<<NN/256,256,0,stream>>>(cnt);
  k_count<<<EE/256,256,0,stream>>>(recv,cnt,pos);
  k_scan<<<1,256,0,stream>>>(cnt,off);
  k_fill<<<EE/256,256,0,stream>>>(recv,off,pos,elist);
  k_gather<<<NN,256,0,stream>>>(x,mix,Yp,CG,senders,off,elist,agg);
  k_tail<<<NN/2,256,0,stream>>>(agg,x,Wdown,u3i,u3v,u2i,u2v,u1i,u1v,uoff,
                                w3,w2,w1,Wsc,Wout,species,out);
}